// Round 5
// baseline (429.806 us; speedup 1.0000x reference)
//
#include <hip/hip_runtime.h>

typedef __attribute__((ext_vector_type(8))) short bf16x8;
typedef __attribute__((ext_vector_type(4))) float f32x4;

static __device__ __forceinline__ unsigned short f2bf(float f) {
    unsigned int u = __builtin_bit_cast(unsigned int, f);
    u += 0x7fffu + ((u >> 16) & 1u);   // round-to-nearest-even
    return (unsigned short)(u >> 16);
}
static __device__ __forceinline__ float bf2f(unsigned short h) {
    unsigned int u = ((unsigned int)h) << 16;
    return __builtin_bit_cast(float, u);
}
// async global->LDS, 16B per lane; LDS dest = wave-uniform base + lane*16
static __device__ __forceinline__ void gload_lds16(const void* g, void* l) {
    __builtin_amdgcn_global_load_lds(
        (const __attribute__((address_space(1))) void*)g,
        (__attribute__((address_space(3))) void*)l, 16, 0, 0);
}

// ------------------------------------------- fp32 -> bf16 (x and bias)
__global__ void convert_bf16(const float* __restrict__ src,
                             unsigned short* __restrict__ dst, int n8) {
    int i = blockIdx.x * blockDim.x + threadIdx.x;
    if (i >= n8) return;
    const float4* s4 = (const float4*)src;
    float4 a = s4[2 * i], b = s4[2 * i + 1];
    uint4 u;
    u.x = (unsigned)f2bf(a.x) | ((unsigned)f2bf(a.y) << 16);
    u.y = (unsigned)f2bf(a.z) | ((unsigned)f2bf(a.w) << 16);
    u.z = (unsigned)f2bf(b.x) | ((unsigned)f2bf(b.y) << 16);
    u.w = (unsigned)f2bf(b.z) | ((unsigned)f2bf(b.w) << 16);
    *(uint4*)(dst + 8 * (size_t)i) = u;
}

// ---------------------------- transpose+convert all 4 weights (1024x1024)
__global__ void transpose_convert4(const float* __restrict__ W0,
                                   const float* __restrict__ W1,
                                   const float* __restrict__ W2,
                                   const float* __restrict__ W3,
                                   unsigned short* __restrict__ T0,
                                   unsigned short* __restrict__ T1,
                                   unsigned short* __restrict__ T2,
                                   unsigned short* __restrict__ T3) {
    const float* W = (blockIdx.z == 0) ? W0 : (blockIdx.z == 1) ? W1
                     : (blockIdx.z == 2) ? W2 : W3;
    unsigned short* Wt = (blockIdx.z == 0) ? T0 : (blockIdx.z == 1) ? T1
                         : (blockIdx.z == 2) ? T2 : T3;
    __shared__ float t[32][33];
    int tx = threadIdx.x, ty = threadIdx.y;          // 32 x 8
    int x0 = blockIdx.x * 32, y0 = blockIdx.y * 32;
    for (int i = 0; i < 4; i++)
        t[ty + 8 * i][tx] = W[(size_t)(y0 + ty + 8 * i) * 1024 + x0 + tx];
    __syncthreads();
    for (int i = 0; i < 4; i++)
        Wt[(size_t)(x0 + ty + 8 * i) * 1024 + y0 + tx] = f2bf(t[tx][ty + 8 * i]);
}

// ------------------------------------------------------------ QKV GEMM
// m97-style: global_load_lds width=16, XOR-swizzled unpadded LDS [128][64].
// physical block = logical block ^ (row & 7).
__launch_bounds__(256)
__global__ void gemm_qkv(const unsigned short* __restrict__ A,
                         const unsigned short* __restrict__ WqT,
                         const unsigned short* __restrict__ WkT,
                         const unsigned short* __restrict__ WvT,
                         const float* __restrict__ bq,
                         const float* __restrict__ bk,
                         const float* __restrict__ bv,
                         const float* __restrict__ alpha,
                         unsigned short* __restrict__ Qb,
                         unsigned short* __restrict__ Kb,
                         unsigned short* __restrict__ Vb) {
    int which = blockIdx.y >> 3;
    const unsigned short* Bt = (which == 0) ? WqT : (which == 1) ? WkT : WvT;
    const float* bias = (which == 0) ? bq : (which == 1) ? bk : bv;
    unsigned short* outb = (which == 0) ? Qb : (which == 1) ? Kb : Vb;

    __shared__ __align__(16) unsigned short As[128][64];
    __shared__ __align__(16) unsigned short Bs[128][64];
    int tid = threadIdx.x;
    int wave = tid >> 6, lane = tid & 63, quad = lane >> 4, l16 = lane & 15;
    int wm = wave & 1, wn = wave >> 1;
    int lrow = lane >> 3, lblk = lane & 7;
    int swz = ((lblk ^ lrow) * 8);                   // swizzled k-offset
    int m0 = blockIdx.x * 128, n0 = (blockIdx.y & 7) * 128;
    f32x4 acc[4][4] = {};

    for (int kt = 0; kt < 16; kt++) {
        int k0 = kt * 64;
        for (int i = 0; i < 4; i++) {
            int rbase = i * 32 + wave * 8;
            gload_lds16(&A[(size_t)(m0 + rbase + lrow) * 1024 + k0 + swz],
                        &As[rbase][0]);
            gload_lds16(&Bt[(size_t)(n0 + rbase + lrow) * 1024 + k0 + swz],
                        &Bs[rbase][0]);
        }
        __syncthreads();
        for (int ks = 0; ks < 2; ks++) {
            int pblk = ((ks * 4 + quad) ^ (l16 & 7)) * 8;
            bf16x8 af[4], bf_[4];
            for (int i = 0; i < 4; i++)
                af[i] = *(const bf16x8*)&As[64 * wm + 16 * i + l16][pblk];
            for (int j = 0; j < 4; j++)
                bf_[j] = *(const bf16x8*)&Bs[64 * wn + 16 * j + l16][pblk];
            for (int i = 0; i < 4; i++)
                for (int j = 0; j < 4; j++)
                    acc[i][j] = __builtin_amdgcn_mfma_f32_16x16x32_bf16(
                        af[i], bf_[j], acc[i][j], 0, 0, 0);
        }
        __syncthreads();
    }

    for (int i = 0; i < 4; i++)
        for (int j = 0; j < 4; j++) {
            int colb = n0 + 64 * wn + 16 * j + l16;
            int h = colb >> 6, dk = colb & 63;
            for (int r = 0; r < 4; r++) {
                int row = m0 + 64 * wm + 16 * i + quad * 4 + r;
                int bb = row >> 11, nn = row & 2047;
                float v = acc[i][j][r] + bias[colb];
                float s = (which == 0) ? 0.125f : (1.0f + alpha[bb * 2048 + nn]);
                outb[((size_t)(bb * 16 + h) * 2048 + nn) * 64 + dk] = f2bf(v * s);
            }
        }
}

// ------------------------------------------------ out projection GEMM (fp32)
__launch_bounds__(256)
__global__ void gemm_out(const unsigned short* __restrict__ A,
                         const unsigned short* __restrict__ Bt,
                         const float* __restrict__ bias,
                         float* __restrict__ outf) {
    __shared__ __align__(16) unsigned short As[128][64];
    __shared__ __align__(16) unsigned short Bs[128][64];
    int tid = threadIdx.x;
    int wave = tid >> 6, lane = tid & 63, quad = lane >> 4, l16 = lane & 15;
    int wm = wave & 1, wn = wave >> 1;
    int lrow = lane >> 3, lblk = lane & 7;
    int swz = ((lblk ^ lrow) * 8);
    int m0 = blockIdx.x * 128, n0 = blockIdx.y * 128;
    f32x4 acc[4][4] = {};

    for (int kt = 0; kt < 16; kt++) {
        int k0 = kt * 64;
        for (int i = 0; i < 4; i++) {
            int rbase = i * 32 + wave * 8;
            gload_lds16(&A[(size_t)(m0 + rbase + lrow) * 1024 + k0 + swz],
                        &As[rbase][0]);
            gload_lds16(&Bt[(size_t)(n0 + rbase + lrow) * 1024 + k0 + swz],
                        &Bs[rbase][0]);
        }
        __syncthreads();
        for (int ks = 0; ks < 2; ks++) {
            int pblk = ((ks * 4 + quad) ^ (l16 & 7)) * 8;
            bf16x8 af[4], bf_[4];
            for (int i = 0; i < 4; i++)
                af[i] = *(const bf16x8*)&As[64 * wm + 16 * i + l16][pblk];
            for (int j = 0; j < 4; j++)
                bf_[j] = *(const bf16x8*)&Bs[64 * wn + 16 * j + l16][pblk];
            for (int i = 0; i < 4; i++)
                for (int j = 0; j < 4; j++)
                    acc[i][j] = __builtin_amdgcn_mfma_f32_16x16x32_bf16(
                        af[i], bf_[j], acc[i][j], 0, 0, 0);
        }
        __syncthreads();
    }

    for (int i = 0; i < 4; i++)
        for (int j = 0; j < 4; j++) {
            int colb = n0 + 64 * wn + 16 * j + l16;
            for (int r = 0; r < 4; r++) {
                int row = m0 + 64 * wm + 16 * i + quad * 4 + r;
                outf[(size_t)row * 1024 + colb] = acc[i][j][r] + bias[colb];
            }
        }
}

// ----------------------------------- V transpose: [b][h][n][dk] -> [b][h][dk][n]
__global__ void transpose_v(const unsigned short* __restrict__ src,
                            unsigned short* __restrict__ dst) {
    __shared__ unsigned short t[64][72];
    int bh = blockIdx.y;
    int n0 = blockIdx.x * 64;
    src += (size_t)bh * 2048 * 64;
    dst += (size_t)bh * 64 * 2048;
    int tid = threadIdx.x;
    for (int i = 0; i < 2; i++) {
        int c = tid + i * 256;
        int row = c >> 3, k8 = (c & 7) * 8;
        bf16x8 v = *(const bf16x8*)(src + (size_t)(n0 + row) * 64 + k8);
        for (int j = 0; j < 8; j++) t[k8 + j][row] = ((unsigned short*)&v)[j];
    }
    __syncthreads();
    for (int i = 0; i < 2; i++) {
        int c = tid + i * 256;
        int dk = c >> 3, n8 = (c & 7) * 8;
        bf16x8 v;
        for (int j = 0; j < 8; j++) ((unsigned short*)&v)[j] = t[dk][n8 + j];
        *(bf16x8*)(dst + (size_t)dk * 2048 + n0 + n8) = v;
    }
}

// ----------------------------------------------------- flash attention
// BARRIER-FREE: each wave owns a 16-q band; K and V fragments are loaded
// directly from global (contiguous 16B per lane thanks to [key][dk] /
// [dk][key] layouts); only P round-trips through per-wave LDS. Bias staged
// per-wave via 2 coalesced b128 loads. No __syncthreads anywhere.
__launch_bounds__(256, 4)
__global__ void attn_kernel(const unsigned short* __restrict__ Q,
                            const unsigned short* __restrict__ K,
                            const unsigned short* __restrict__ Vt,
                            const unsigned short* __restrict__ biasb,
                            unsigned short* __restrict__ Y) {
    __shared__ __align__(16) unsigned short Ps[4][16][72];  // per-wave, swizzled
    __shared__ __align__(16) unsigned short Bw[4][16][68];  // per-wave bias tile
    int tid = threadIdx.x;
    int wave = tid >> 6, lane = tid & 63, quad = lane >> 4, l16 = lane & 15;
    int b = blockIdx.z, h = blockIdx.y, q0 = blockIdx.x * 64;
    size_t headoff = (size_t)(b * 16 + h) * 2048 * 64;
    const unsigned short* Kp = K + headoff;
    const unsigned short* Vp = Vt + headoff;

    bf16x8 aq[2];
    {
        const unsigned short* qp = Q + headoff + (size_t)(q0 + 16 * wave + l16) * 64;
        aq[0] = *(const bf16x8*)&qp[quad * 8];
        aq[1] = *(const bf16x8*)&qp[32 + quad * 8];
    }
    bf16x8 ones;
    for (int j = 0; j < 8; j++) ones[j] = (short)0x3F80;   // bf16 1.0

    f32x4 oacc[4] = {};
    f32x4 lacc = {};
    const unsigned short* bbase =
        biasb + ((size_t)b * 2048 + q0 + 16 * wave) * 2048;
    int brow0 = lane >> 3, bblk0 = lane & 7;   // bias staging: chunks lane, lane+64

    for (int mt = 0; mt < 32; mt++) {
        int m0 = mt * 64;

        // ---- K fragments direct from global (B-layout: n=key, k=dk)
        bf16x8 kb[4][2];
        for (int c = 0; c < 4; c++)
            for (int ks = 0; ks < 2; ks++)
                kb[c][ks] = *(const bf16x8*)&Kp[(size_t)(m0 + c * 16 + l16) * 64 +
                                                ks * 32 + quad * 8];
        // ---- stage this wave's 16x64 bias tile (2 coalesced b128 loads)
        *(bf16x8*)&Bw[wave][brow0][bblk0 * 8] =
            *(const bf16x8*)&bbase[(size_t)brow0 * 2048 + m0 + bblk0 * 8];
        *(bf16x8*)&Bw[wave][brow0 + 8][bblk0 * 8] =
            *(const bf16x8*)&bbase[(size_t)(brow0 + 8) * 2048 + m0 + bblk0 * 8];

        // ---- S = Q K^T
        f32x4 sc[4];
        for (int c = 0; c < 4; c++) {
            f32x4 s = {};
            s = __builtin_amdgcn_mfma_f32_16x16x32_bf16(aq[0], kb[c][0], s, 0, 0, 0);
            s = __builtin_amdgcn_mfma_f32_16x16x32_bf16(aq[1], kb[c][1], s, 0, 0, 0);
            sc[c] = s;
        }

        // ---- V fragments direct from global (B-layout: n=dk, k=key) — issued
        // here so their latency overlaps the exp/cvt VALU work below.
        bf16x8 vb[4][2];
        for (int cv = 0; cv < 4; cv++)
            for (int ks = 0; ks < 2; ks++)
                vb[cv][ks] = *(const bf16x8*)&Vp[(size_t)(cv * 16 + l16) * 2048 +
                                                 m0 + ks * 32 + quad * 8];

        // ---- P = exp(S + bias) -> Ps (swizzled, conflict-free)
        for (int c = 0; c < 4; c++) {
            int blkw = ((c * 2 + (l16 >> 3)) + quad) & 7;
            int colw = blkw * 8 + (l16 & 7);
            for (int r = 0; r < 4; r++) {
                float bz = bf2f(Bw[wave][quad * 4 + r][c * 16 + l16]);
                float p = __expf(fminf(sc[c][r] + bz, 30.f));
                Ps[wave][quad * 4 + r][colw] = f2bf(p);
            }
        }

        // ---- O += P V ; l += P 1 (within-wave LDS dependence, no barrier)
        for (int ks = 0; ks < 2; ks++) {
            int blkr = (ks * 4 + quad + (l16 >> 2)) & 7;
            bf16x8 pf = *(const bf16x8*)&Ps[wave][l16][blkr * 8];
            lacc = __builtin_amdgcn_mfma_f32_16x16x32_bf16(pf, ones, lacc, 0, 0, 0);
            for (int cv = 0; cv < 4; cv++)
                oacc[cv] = __builtin_amdgcn_mfma_f32_16x16x32_bf16(
                    pf, vb[cv][ks], oacc[cv], 0, 0, 0);
        }
    }

    float invl[4];
    for (int r = 0; r < 4; r++) invl[r] = 1.0f / lacc[r];
    for (int cv = 0; cv < 4; cv++)
        for (int r = 0; r < 4; r++) {
            float val = oacc[cv][r] * invl[r];
            int qrow = q0 + 16 * wave + quad * 4 + r;
            int d = h * 64 + cv * 16 + l16;
            Y[((size_t)b * 2048 + qrow) * 1024 + d] = f2bf(val);
        }
}

// ---------------------------------------------------------------- launcher
extern "C" void kernel_launch(void* const* d_in, const int* in_sizes, int n_in,
                              void* d_out, int out_size, void* d_ws, size_t ws_size,
                              hipStream_t stream) {
    const float* x     = (const float*)d_in[0];
    const float* alpha = (const float*)d_in[1];
    const float* bias  = (const float*)d_in[2];
    const float* Wq    = (const float*)d_in[3];
    const float* bq    = (const float*)d_in[4];
    const float* Wk    = (const float*)d_in[5];
    const float* bk    = (const float*)d_in[6];
    const float* Wv    = (const float*)d_in[7];
    const float* bv    = (const float*)d_in[8];
    const float* Wo    = (const float*)d_in[9];
    const float* bo    = (const float*)d_in[10];
    float* out = (float*)d_out;

    char* ws = (char*)d_ws;
    const size_t MB = 1048576;
    unsigned short* xb    = (unsigned short*)(ws);           // [0,8M), Yb later
    unsigned short* wqt   = (unsigned short*)(ws + 8 * MB);
    unsigned short* wkt   = (unsigned short*)(ws + 10 * MB);
    unsigned short* wvt   = (unsigned short*)(ws + 12 * MB);
    unsigned short* wot   = (unsigned short*)(ws + 14 * MB);
    unsigned short* Qb    = (unsigned short*)(ws + 16 * MB);
    unsigned short* Kb    = (unsigned short*)(ws + 24 * MB);
    unsigned short* Vb    = (unsigned short*)(ws + 32 * MB);
    unsigned short* Vtb   = (unsigned short*)(ws + 40 * MB);
    unsigned short* biasb = (unsigned short*)(ws + 48 * MB); // 16 MB
    unsigned short* Yb    = xb;

    convert_bf16<<<2048, 256, 0, stream>>>(x, xb, 524288);
    convert_bf16<<<4096, 256, 0, stream>>>(bias, biasb, 1048576);
    transpose_convert4<<<dim3(32, 32, 4), dim3(32, 8), 0, stream>>>(
        Wq, Wk, Wv, Wo, wqt, wkt, wvt, wot);

    gemm_qkv<<<dim3(32, 24), 256, 0, stream>>>(
        xb, wqt, wkt, wvt, bq, bk, bv, alpha, Qb, Kb, Vb);

    transpose_v<<<dim3(32, 32), 256, 0, stream>>>(Vb, Vtb);

    attn_kernel<<<dim3(32, 16, 2), 256, 0, stream>>>(Qb, Kb, Vtb, biasb, Yb);

    gemm_out<<<dim3(32, 8), 256, 0, stream>>>(Yb, wot, bo, out);
}

// Round 6
// 272.528 us; speedup vs baseline: 1.5771x; 1.5771x over previous
//
#include <hip/hip_runtime.h>

typedef __attribute__((ext_vector_type(8))) short bf16x8;
typedef __attribute__((ext_vector_type(4))) float f32x4;

static __device__ __forceinline__ unsigned short f2bf(float f) {
    unsigned int u = __builtin_bit_cast(unsigned int, f);
    u += 0x7fffu + ((u >> 16) & 1u);   // round-to-nearest-even
    return (unsigned short)(u >> 16);
}
static __device__ __forceinline__ float bf2f(unsigned short h) {
    unsigned int u = ((unsigned int)h) << 16;
    return __builtin_bit_cast(float, u);
}
// async global->LDS, 16B per lane; LDS dest = wave-uniform base + lane*16
static __device__ __forceinline__ void gload_lds16(const void* g, void* l) {
    __builtin_amdgcn_global_load_lds(
        (const __attribute__((address_space(1))) void*)g,
        (__attribute__((address_space(3))) void*)l, 16, 0, 0);
}

// ------------------------------------------- fp32 -> bf16 (x)
__global__ void convert_bf16(const float* __restrict__ src,
                             unsigned short* __restrict__ dst, int n8) {
    int i = blockIdx.x * blockDim.x + threadIdx.x;
    if (i >= n8) return;
    const float4* s4 = (const float4*)src;
    float4 a = s4[2 * i], b = s4[2 * i + 1];
    uint4 u;
    u.x = (unsigned)f2bf(a.x) | ((unsigned)f2bf(a.y) << 16);
    u.y = (unsigned)f2bf(a.z) | ((unsigned)f2bf(a.w) << 16);
    u.z = (unsigned)f2bf(b.x) | ((unsigned)f2bf(b.y) << 16);
    u.w = (unsigned)f2bf(b.z) | ((unsigned)f2bf(b.w) << 16);
    *(uint4*)(dst + 8 * (size_t)i) = u;
}

// -------------------- bias: fp32 [b][q][k] -> bf16 in MFMA C-fragment order
// out[((b*16+qt)*32+mt)*8192 + ((e*4+w)*64+lane)*16 + (c*4+r)]
//   = bias[b][qt*128+e*64+w*16+quad*4+r][mt*64+c*16+l16]
// grid (32 mt, 16 qt, 2 b), block 256.
__global__ void bias_permute(const float* __restrict__ src,
                             unsigned short* __restrict__ dst) {
    int mt = blockIdx.x, qt = blockIdx.y, b = blockIdx.z;
    int tid = threadIdx.x, w = tid >> 6, lane = tid & 63;
    int quad = lane >> 4, l16 = lane & 15;
    const float* s = src + (size_t)b * 2048 * 2048;
    unsigned short* d = dst + (((size_t)(b * 16 + qt) * 32 + mt) * 8192);
    for (int e = 0; e < 2; e++) {
        unsigned short vals[16];
        for (int c = 0; c < 4; c++)
            for (int r = 0; r < 4; r++) {
                int q = qt * 128 + e * 64 + w * 16 + quad * 4 + r;
                int k = mt * 64 + c * 16 + l16;
                vals[c * 4 + r] = f2bf(s[(size_t)q * 2048 + k]);
            }
        unsigned short* o = d + ((size_t)((e * 4 + w) * 64 + lane)) * 16;
        *(bf16x8*)&o[0] = *(bf16x8*)&vals[0];
        *(bf16x8*)&o[8] = *(bf16x8*)&vals[8];
    }
}

// ---------------------------- transpose+convert all 4 weights (1024x1024)
__global__ void transpose_convert4(const float* __restrict__ W0,
                                   const float* __restrict__ W1,
                                   const float* __restrict__ W2,
                                   const float* __restrict__ W3,
                                   unsigned short* __restrict__ T0,
                                   unsigned short* __restrict__ T1,
                                   unsigned short* __restrict__ T2,
                                   unsigned short* __restrict__ T3) {
    const float* W = (blockIdx.z == 0) ? W0 : (blockIdx.z == 1) ? W1
                     : (blockIdx.z == 2) ? W2 : W3;
    unsigned short* Wt = (blockIdx.z == 0) ? T0 : (blockIdx.z == 1) ? T1
                         : (blockIdx.z == 2) ? T2 : T3;
    __shared__ float t[32][33];
    int tx = threadIdx.x, ty = threadIdx.y;          // 32 x 8
    int x0 = blockIdx.x * 32, y0 = blockIdx.y * 32;
    for (int i = 0; i < 4; i++)
        t[ty + 8 * i][tx] = W[(size_t)(y0 + ty + 8 * i) * 1024 + x0 + tx];
    __syncthreads();
    for (int i = 0; i < 4; i++)
        Wt[(size_t)(x0 + ty + 8 * i) * 1024 + y0 + tx] = f2bf(t[tx][ty + 8 * i]);
}

// ------------------------------------------------------------ QKV GEMM
__launch_bounds__(256)
__global__ void gemm_qkv(const unsigned short* __restrict__ A,
                         const unsigned short* __restrict__ WqT,
                         const unsigned short* __restrict__ WkT,
                         const unsigned short* __restrict__ WvT,
                         const float* __restrict__ bq,
                         const float* __restrict__ bk,
                         const float* __restrict__ bv,
                         const float* __restrict__ alpha,
                         unsigned short* __restrict__ Qb,
                         unsigned short* __restrict__ Kb,
                         unsigned short* __restrict__ Vb) {
    int which = blockIdx.y >> 3;
    const unsigned short* Bt = (which == 0) ? WqT : (which == 1) ? WkT : WvT;
    const float* bias = (which == 0) ? bq : (which == 1) ? bk : bv;
    unsigned short* outb = (which == 0) ? Qb : (which == 1) ? Kb : Vb;

    __shared__ __align__(16) unsigned short As[128][64];
    __shared__ __align__(16) unsigned short Bs[128][64];
    int tid = threadIdx.x;
    int wave = tid >> 6, lane = tid & 63, quad = lane >> 4, l16 = lane & 15;
    int wm = wave & 1, wn = wave >> 1;
    int lrow = lane >> 3, lblk = lane & 7;
    int swz = ((lblk ^ lrow) * 8);
    int m0 = blockIdx.x * 128, n0 = (blockIdx.y & 7) * 128;
    f32x4 acc[4][4] = {};

    for (int kt = 0; kt < 16; kt++) {
        int k0 = kt * 64;
        for (int i = 0; i < 4; i++) {
            int rbase = i * 32 + wave * 8;
            gload_lds16(&A[(size_t)(m0 + rbase + lrow) * 1024 + k0 + swz],
                        &As[rbase][0]);
            gload_lds16(&Bt[(size_t)(n0 + rbase + lrow) * 1024 + k0 + swz],
                        &Bs[rbase][0]);
        }
        __syncthreads();
        for (int ks = 0; ks < 2; ks++) {
            int pblk = ((ks * 4 + quad) ^ (l16 & 7)) * 8;
            bf16x8 af[4], bf_[4];
            for (int i = 0; i < 4; i++)
                af[i] = *(const bf16x8*)&As[64 * wm + 16 * i + l16][pblk];
            for (int j = 0; j < 4; j++)
                bf_[j] = *(const bf16x8*)&Bs[64 * wn + 16 * j + l16][pblk];
            for (int i = 0; i < 4; i++)
                for (int j = 0; j < 4; j++)
                    acc[i][j] = __builtin_amdgcn_mfma_f32_16x16x32_bf16(
                        af[i], bf_[j], acc[i][j], 0, 0, 0);
        }
        __syncthreads();
    }

    for (int i = 0; i < 4; i++)
        for (int j = 0; j < 4; j++) {
            int colb = n0 + 64 * wn + 16 * j + l16;
            int h = colb >> 6, dk = colb & 63;
            for (int r = 0; r < 4; r++) {
                int row = m0 + 64 * wm + 16 * i + quad * 4 + r;
                int bb = row >> 11, nn = row & 2047;
                float v = acc[i][j][r] + bias[colb];
                float s = (which == 0) ? 0.125f : (1.0f + alpha[bb * 2048 + nn]);
                outb[((size_t)(bb * 16 + h) * 2048 + nn) * 64 + dk] = f2bf(v * s);
            }
        }
}

// ------------------------------------------------ out projection GEMM (fp32)
__launch_bounds__(256)
__global__ void gemm_out(const unsigned short* __restrict__ A,
                         const unsigned short* __restrict__ Bt,
                         const float* __restrict__ bias,
                         float* __restrict__ outf) {
    __shared__ __align__(16) unsigned short As[128][64];
    __shared__ __align__(16) unsigned short Bs[128][64];
    int tid = threadIdx.x;
    int wave = tid >> 6, lane = tid & 63, quad = lane >> 4, l16 = lane & 15;
    int wm = wave & 1, wn = wave >> 1;
    int lrow = lane >> 3, lblk = lane & 7;
    int swz = ((lblk ^ lrow) * 8);
    int m0 = blockIdx.x * 128, n0 = blockIdx.y * 128;
    f32x4 acc[4][4] = {};

    for (int kt = 0; kt < 16; kt++) {
        int k0 = kt * 64;
        for (int i = 0; i < 4; i++) {
            int rbase = i * 32 + wave * 8;
            gload_lds16(&A[(size_t)(m0 + rbase + lrow) * 1024 + k0 + swz],
                        &As[rbase][0]);
            gload_lds16(&Bt[(size_t)(n0 + rbase + lrow) * 1024 + k0 + swz],
                        &Bs[rbase][0]);
        }
        __syncthreads();
        for (int ks = 0; ks < 2; ks++) {
            int pblk = ((ks * 4 + quad) ^ (l16 & 7)) * 8;
            bf16x8 af[4], bf_[4];
            for (int i = 0; i < 4; i++)
                af[i] = *(const bf16x8*)&As[64 * wm + 16 * i + l16][pblk];
            for (int j = 0; j < 4; j++)
                bf_[j] = *(const bf16x8*)&Bs[64 * wn + 16 * j + l16][pblk];
            for (int i = 0; i < 4; i++)
                for (int j = 0; j < 4; j++)
                    acc[i][j] = __builtin_amdgcn_mfma_f32_16x16x32_bf16(
                        af[i], bf_[j], acc[i][j], 0, 0, 0);
        }
        __syncthreads();
    }

    for (int i = 0; i < 4; i++)
        for (int j = 0; j < 4; j++) {
            int colb = n0 + 64 * wn + 16 * j + l16;
            for (int r = 0; r < 4; r++) {
                int row = m0 + 64 * wm + 16 * i + quad * 4 + r;
                outf[(size_t)row * 1024 + colb] = acc[i][j][r] + bias[colb];
            }
        }
}

// ----------------------------------- V transpose: [b][h][n][dk] -> [b][h][dk][n]
__global__ void transpose_v(const unsigned short* __restrict__ src,
                            unsigned short* __restrict__ dst) {
    __shared__ unsigned short t[64][72];
    int bh = blockIdx.y;
    int n0 = blockIdx.x * 64;
    src += (size_t)bh * 2048 * 64;
    dst += (size_t)bh * 64 * 2048;
    int tid = threadIdx.x;
    for (int i = 0; i < 2; i++) {
        int c = tid + i * 256;
        int row = c >> 3, k8 = (c & 7) * 8;
        bf16x8 v = *(const bf16x8*)(src + (size_t)(n0 + row) * 64 + k8);
        for (int j = 0; j < 8; j++) t[k8 + j][row] = ((unsigned short*)&v)[j];
    }
    __syncthreads();
    for (int i = 0; i < 2; i++) {
        int c = tid + i * 256;
        int dk = c >> 3, n8 = (c & 7) * 8;
        bf16x8 v;
        for (int j = 0; j < 8; j++) ((unsigned short*)&v)[j] = t[dk][n8 + j];
        *(bf16x8*)(dst + (size_t)dk * 2048 + n0 + n8) = v;
    }
}

// ----------------------------------------------------- flash attention
// grid (16, 16, 2): 128 q-rows per WG, 2 bands of 16 per wave. K/V staged to
// LDS via global_load_lds (XOR swizzle, unpadded) and their fragments feed
// BOTH bands (halves LDS frag traffic per q). Bias read directly from global
// in pre-permuted per-lane fragment order (2 coalesced b128 per band). P
// round-trips per-wave LDS (swizzled, no barrier). l via MFMA with B=ones.
__launch_bounds__(256)
__global__ void attn_kernel(const unsigned short* __restrict__ Q,
                            const unsigned short* __restrict__ K,
                            const unsigned short* __restrict__ Vt,
                            const unsigned short* __restrict__ biasP,
                            unsigned short* __restrict__ Y) {
    __shared__ __align__(16) unsigned short Ks[64][64];     // [key][dk] swizzled
    __shared__ __align__(16) unsigned short Vs[64][64];     // [dk][key] swizzled
    __shared__ __align__(16) unsigned short Ps[4][32][72];  // per-wave, 2 bands
    int tid = threadIdx.x;
    int wave = tid >> 6, lane = tid & 63, quad = lane >> 4, l16 = lane & 15;
    int b = blockIdx.z, h = blockIdx.y, qt = blockIdx.x, q0 = qt * 128;
    size_t headoff = (size_t)(b * 16 + h) * 2048 * 64;
    const unsigned short* Kp = K + headoff;
    const unsigned short* Vp = Vt + headoff;
    int lrow = lane >> 3, lblk = lane & 7;
    int swz = (lblk ^ lrow) * 8;

    bf16x8 aq[2][2];
    for (int e = 0; e < 2; e++) {
        const unsigned short* qp =
            Q + headoff + (size_t)(q0 + e * 64 + wave * 16 + l16) * 64;
        aq[e][0] = *(const bf16x8*)&qp[quad * 8];
        aq[e][1] = *(const bf16x8*)&qp[32 + quad * 8];
    }
    bf16x8 ones;
    for (int j = 0; j < 8; j++) ones[j] = (short)0x3F80;   // bf16 1.0

    f32x4 oacc[2][4] = {};
    f32x4 lacc[2] = {};
    const unsigned short* bP = biasP + (size_t)(b * 16 + qt) * 32 * 8192;

    for (int mt = 0; mt < 32; mt++) {
        int m0 = mt * 64;
        // ---- stage K (rows=key) and V^T (rows=dk) via async DMA, swizzled
        for (int i = 0; i < 2; i++) {
            int rbase = wave * 16 + i * 8;
            gload_lds16(&Kp[(size_t)(m0 + rbase + lrow) * 64 + swz], &Ks[rbase][0]);
            gload_lds16(&Vp[(size_t)(rbase + lrow) * 2048 + m0 + swz], &Vs[rbase][0]);
        }
        // ---- bias fragments, pre-permuted: 2 coalesced b128 per band
        const unsigned short* bt = bP + (size_t)mt * 8192;
        bf16x8 bz[2][2];
        for (int e = 0; e < 2; e++) {
            const unsigned short* p = bt + (size_t)((e * 4 + wave) * 64 + lane) * 16;
            bz[e][0] = *(const bf16x8*)&p[0];
            bz[e][1] = *(const bf16x8*)&p[8];
        }
        __syncthreads();

        // ---- S = Q K^T for both bands (K frags read once)
        f32x4 sc[2][4];
        for (int c = 0; c < 4; c++) {
            f32x4 s0 = {}, s1 = {};
            for (int ks = 0; ks < 2; ks++) {
                bf16x8 kf = *(const bf16x8*)&Ks[c * 16 + l16]
                                               [((ks * 4 + quad) ^ (l16 & 7)) * 8];
                s0 = __builtin_amdgcn_mfma_f32_16x16x32_bf16(aq[0][ks], kf, s0, 0, 0, 0);
                s1 = __builtin_amdgcn_mfma_f32_16x16x32_bf16(aq[1][ks], kf, s1, 0, 0, 0);
            }
            sc[0][c] = s0;
            sc[1][c] = s1;
        }

        // ---- P = exp(S + bias) -> Ps (swizzled scalar writes, conflict-free)
        for (int e = 0; e < 2; e++)
            for (int c = 0; c < 4; c++) {
                int colw = (((c * 2 + (l16 >> 3)) + quad) & 7) * 8 + (l16 & 7);
                for (int r = 0; r < 4; r++) {
                    float bb = bf2f(((unsigned short*)&bz[e][c >> 1])[(c & 1) * 4 + r]);
                    float p = __expf(fminf(sc[e][c][r] + bb, 30.f));
                    Ps[wave][e * 16 + quad * 4 + r][colw] = f2bf(p);
                }
            }

        // ---- O += P V ; l += P 1 (V frags read once, feed both bands)
        for (int ks = 0; ks < 2; ks++) {
            int blkr = (ks * 4 + quad + (l16 >> 2)) & 7;
            bf16x8 pf0 = *(const bf16x8*)&Ps[wave][l16][blkr * 8];
            bf16x8 pf1 = *(const bf16x8*)&Ps[wave][16 + l16][blkr * 8];
            lacc[0] = __builtin_amdgcn_mfma_f32_16x16x32_bf16(pf0, ones, lacc[0], 0, 0, 0);
            lacc[1] = __builtin_amdgcn_mfma_f32_16x16x32_bf16(pf1, ones, lacc[1], 0, 0, 0);
            for (int cv = 0; cv < 4; cv++) {
                bf16x8 vf = *(const bf16x8*)&Vs[cv * 16 + l16]
                                               [((ks * 4 + quad) ^ (l16 & 7)) * 8];
                oacc[0][cv] = __builtin_amdgcn_mfma_f32_16x16x32_bf16(pf0, vf, oacc[0][cv], 0, 0, 0);
                oacc[1][cv] = __builtin_amdgcn_mfma_f32_16x16x32_bf16(pf1, vf, oacc[1][cv], 0, 0, 0);
            }
        }
        __syncthreads();
    }

    for (int e = 0; e < 2; e++) {
        float invl[4];
        for (int r = 0; r < 4; r++) invl[r] = 1.0f / lacc[e][r];
        for (int cv = 0; cv < 4; cv++)
            for (int r = 0; r < 4; r++) {
                int qrow = q0 + e * 64 + 16 * wave + quad * 4 + r;
                int d = h * 64 + cv * 16 + l16;
                Y[((size_t)b * 2048 + qrow) * 1024 + d] =
                    f2bf(oacc[e][cv][r] * invl[r]);
            }
    }
}

// ---------------------------------------------------------------- launcher
extern "C" void kernel_launch(void* const* d_in, const int* in_sizes, int n_in,
                              void* d_out, int out_size, void* d_ws, size_t ws_size,
                              hipStream_t stream) {
    const float* x     = (const float*)d_in[0];
    const float* alpha = (const float*)d_in[1];
    const float* bias  = (const float*)d_in[2];
    const float* Wq    = (const float*)d_in[3];
    const float* bq    = (const float*)d_in[4];
    const float* Wk    = (const float*)d_in[5];
    const float* bk    = (const float*)d_in[6];
    const float* Wv    = (const float*)d_in[7];
    const float* bv    = (const float*)d_in[8];
    const float* Wo    = (const float*)d_in[9];
    const float* bo    = (const float*)d_in[10];
    float* out = (float*)d_out;

    char* ws = (char*)d_ws;
    const size_t MB = 1048576;
    unsigned short* xb    = (unsigned short*)(ws);           // [0,8M), Yb later
    unsigned short* wqt   = (unsigned short*)(ws + 8 * MB);
    unsigned short* wkt   = (unsigned short*)(ws + 10 * MB);
    unsigned short* wvt   = (unsigned short*)(ws + 12 * MB);
    unsigned short* wot   = (unsigned short*)(ws + 14 * MB);
    unsigned short* Qb    = (unsigned short*)(ws + 16 * MB);
    unsigned short* Kb    = (unsigned short*)(ws + 24 * MB);
    unsigned short* Vb    = (unsigned short*)(ws + 32 * MB);
    unsigned short* Vtb   = (unsigned short*)(ws + 40 * MB);
    unsigned short* biasP = (unsigned short*)(ws + 48 * MB); // 16 MB
    unsigned short* Yb    = xb;

    convert_bf16<<<2048, 256, 0, stream>>>(x, xb, 524288);
    bias_permute<<<dim3(32, 16, 2), 256, 0, stream>>>(bias, biasP);
    transpose_convert4<<<dim3(32, 32, 4), dim3(32, 8), 0, stream>>>(
        Wq, Wk, Wv, Wo, wqt, wkt, wvt, wot);

    gemm_qkv<<<dim3(32, 24), 256, 0, stream>>>(
        xb, wqt, wkt, wvt, bq, bk, bv, alpha, Qb, Kb, Vb);

    transpose_v<<<dim3(32, 32), 256, 0, stream>>>(Vb, Vtb);

    attn_kernel<<<dim3(16, 16, 2), 256, 0, stream>>>(Qb, Kb, Vtb, biasP, Yb);

    gemm_out<<<dim3(32, 8), 256, 0, stream>>>(Yb, wot, bo, out);
}

// Round 7
// 255.080 us; speedup vs baseline: 1.6850x; 1.0684x over previous
//
#include <hip/hip_runtime.h>

typedef __attribute__((ext_vector_type(8))) short bf16x8;
typedef __attribute__((ext_vector_type(4))) float f32x4;

#define LOG2E 1.4426950408889634f

static __device__ __forceinline__ unsigned short f2bf(float f) {
    unsigned int u = __builtin_bit_cast(unsigned int, f);
    u += 0x7fffu + ((u >> 16) & 1u);   // round-to-nearest-even
    return (unsigned short)(u >> 16);
}
static __device__ __forceinline__ float bf2f(unsigned short h) {
    unsigned int u = ((unsigned int)h) << 16;
    return __builtin_bit_cast(float, u);
}
// async global->LDS, 16B per lane; LDS dest = wave-uniform base + lane*16
static __device__ __forceinline__ void gload_lds16(const void* g, void* l) {
    __builtin_amdgcn_global_load_lds(
        (const __attribute__((address_space(1))) void*)g,
        (__attribute__((address_space(3))) void*)l, 16, 0, 0);
}

// ------------------------------------------- fp32 -> bf16 (x)
__global__ void convert_bf16(const float* __restrict__ src,
                             unsigned short* __restrict__ dst, int n8) {
    int i = blockIdx.x * blockDim.x + threadIdx.x;
    if (i >= n8) return;
    const float4* s4 = (const float4*)src;
    float4 a = s4[2 * i], b = s4[2 * i + 1];
    uint4 u;
    u.x = (unsigned)f2bf(a.x) | ((unsigned)f2bf(a.y) << 16);
    u.y = (unsigned)f2bf(a.z) | ((unsigned)f2bf(a.w) << 16);
    u.z = (unsigned)f2bf(b.x) | ((unsigned)f2bf(b.y) << 16);
    u.w = (unsigned)f2bf(b.z) | ((unsigned)f2bf(b.w) << 16);
    *(uint4*)(dst + 8 * (size_t)i) = u;
}

// -------------------- bias: fp32 [b][q][k] -> bf16*LOG2E in C-fragment order
// out[((b*16+qt)*32+mt)*8192 + ((e*4+w)*64+lane)*16 + (c*4+r)]
__global__ void bias_permute(const float* __restrict__ src,
                             unsigned short* __restrict__ dst) {
    int mt = blockIdx.x, qt = blockIdx.y, b = blockIdx.z;
    int tid = threadIdx.x, w = tid >> 6, lane = tid & 63;
    int quad = lane >> 4, l16 = lane & 15;
    const float* s = src + (size_t)b * 2048 * 2048;
    unsigned short* d = dst + (((size_t)(b * 16 + qt) * 32 + mt) * 8192);
    for (int e = 0; e < 2; e++) {
        unsigned short vals[16];
        for (int c = 0; c < 4; c++)
            for (int r = 0; r < 4; r++) {
                int q = qt * 128 + e * 64 + w * 16 + quad * 4 + r;
                int k = mt * 64 + c * 16 + l16;
                vals[c * 4 + r] = f2bf(s[(size_t)q * 2048 + k] * LOG2E);
            }
        unsigned short* o = d + ((size_t)((e * 4 + w) * 64 + lane)) * 16;
        *(bf16x8*)&o[0] = *(bf16x8*)&vals[0];
        *(bf16x8*)&o[8] = *(bf16x8*)&vals[8];
    }
}

// ---------------------------- transpose+convert all 4 weights (1024x1024)
__global__ void transpose_convert4(const float* __restrict__ W0,
                                   const float* __restrict__ W1,
                                   const float* __restrict__ W2,
                                   const float* __restrict__ W3,
                                   unsigned short* __restrict__ T0,
                                   unsigned short* __restrict__ T1,
                                   unsigned short* __restrict__ T2,
                                   unsigned short* __restrict__ T3) {
    const float* W = (blockIdx.z == 0) ? W0 : (blockIdx.z == 1) ? W1
                     : (blockIdx.z == 2) ? W2 : W3;
    unsigned short* Wt = (blockIdx.z == 0) ? T0 : (blockIdx.z == 1) ? T1
                         : (blockIdx.z == 2) ? T2 : T3;
    __shared__ float t[32][33];
    int tx = threadIdx.x, ty = threadIdx.y;          // 32 x 8
    int x0 = blockIdx.x * 32, y0 = blockIdx.y * 32;
    for (int i = 0; i < 4; i++)
        t[ty + 8 * i][tx] = W[(size_t)(y0 + ty + 8 * i) * 1024 + x0 + tx];
    __syncthreads();
    for (int i = 0; i < 4; i++)
        Wt[(size_t)(x0 + ty + 8 * i) * 1024 + y0 + tx] = f2bf(t[tx][ty + 8 * i]);
}

// ------------------------------------------------------------ QKV GEMM
// Q scaled 0.125*LOG2E -> [b][h][n][dk]; K scaled (1+alpha) -> [b][h][n][dk];
// V scaled (1+alpha) -> TRANSPOSED [b][h][dk][n] (fused transpose_v).
__launch_bounds__(256)
__global__ void gemm_qkv(const unsigned short* __restrict__ A,
                         const unsigned short* __restrict__ WqT,
                         const unsigned short* __restrict__ WkT,
                         const unsigned short* __restrict__ WvT,
                         const float* __restrict__ bq,
                         const float* __restrict__ bk,
                         const float* __restrict__ bv,
                         const float* __restrict__ alpha,
                         unsigned short* __restrict__ Qb,
                         unsigned short* __restrict__ Kb,
                         unsigned short* __restrict__ Vtb) {
    int which = blockIdx.y >> 3;
    const unsigned short* Bt = (which == 0) ? WqT : (which == 1) ? WkT : WvT;
    const float* bias = (which == 0) ? bq : (which == 1) ? bk : bv;

    __shared__ __align__(16) unsigned short As[128][64];
    __shared__ __align__(16) unsigned short Bs[128][64];
    int tid = threadIdx.x;
    int wave = tid >> 6, lane = tid & 63, quad = lane >> 4, l16 = lane & 15;
    int wm = wave & 1, wn = wave >> 1;
    int lrow = lane >> 3, lblk = lane & 7;
    int swz = ((lblk ^ lrow) * 8);
    int m0 = blockIdx.x * 128, n0 = (blockIdx.y & 7) * 128;
    f32x4 acc[4][4] = {};

    for (int kt = 0; kt < 16; kt++) {
        int k0 = kt * 64;
        for (int i = 0; i < 4; i++) {
            int rbase = i * 32 + wave * 8;
            gload_lds16(&A[(size_t)(m0 + rbase + lrow) * 1024 + k0 + swz],
                        &As[rbase][0]);
            gload_lds16(&Bt[(size_t)(n0 + rbase + lrow) * 1024 + k0 + swz],
                        &Bs[rbase][0]);
        }
        __syncthreads();
        for (int ks = 0; ks < 2; ks++) {
            int pblk = ((ks * 4 + quad) ^ (l16 & 7)) * 8;
            bf16x8 af[4], bf_[4];
            for (int i = 0; i < 4; i++)
                af[i] = *(const bf16x8*)&As[64 * wm + 16 * i + l16][pblk];
            for (int j = 0; j < 4; j++)
                bf_[j] = *(const bf16x8*)&Bs[64 * wn + 16 * j + l16][pblk];
            for (int i = 0; i < 4; i++)
                for (int j = 0; j < 4; j++)
                    acc[i][j] = __builtin_amdgcn_mfma_f32_16x16x32_bf16(
                        af[i], bf_[j], acc[i][j], 0, 0, 0);
        }
        __syncthreads();
    }

    for (int i = 0; i < 4; i++)
        for (int j = 0; j < 4; j++) {
            int colb = n0 + 64 * wn + 16 * j + l16;
            int h = colb >> 6, dk = colb & 63;
            int row0 = m0 + 64 * wm + 16 * i + quad * 4;
            int bb = row0 >> 11, nn0 = row0 & 2047;
            if (which == 2) {
                unsigned short v4[4];
                for (int r = 0; r < 4; r++) {
                    float v = acc[i][j][r] + bias[colb];
                    v4[r] = f2bf(v * (1.0f + alpha[bb * 2048 + nn0 + r]));
                }
                uint2 u;
                u.x = (unsigned)v4[0] | ((unsigned)v4[1] << 16);
                u.y = (unsigned)v4[2] | ((unsigned)v4[3] << 16);
                *(uint2*)&Vtb[((size_t)(bb * 16 + h) * 64 + dk) * 2048 + nn0] = u;
            } else {
                unsigned short* outb = (which == 0) ? Qb : Kb;
                for (int r = 0; r < 4; r++) {
                    float v = acc[i][j][r] + bias[colb];
                    float s = (which == 0) ? (0.125f * LOG2E)
                                           : (1.0f + alpha[bb * 2048 + nn0 + r]);
                    outb[((size_t)(bb * 16 + h) * 2048 + nn0 + r) * 64 + dk] =
                        f2bf(v * s);
                }
            }
        }
}

// ------------------------------------------------ out projection GEMM (fp32)
__launch_bounds__(256)
__global__ void gemm_out(const unsigned short* __restrict__ A,
                         const unsigned short* __restrict__ Bt,
                         const float* __restrict__ bias,
                         float* __restrict__ outf) {
    __shared__ __align__(16) unsigned short As[128][64];
    __shared__ __align__(16) unsigned short Bs[128][64];
    int tid = threadIdx.x;
    int wave = tid >> 6, lane = tid & 63, quad = lane >> 4, l16 = lane & 15;
    int wm = wave & 1, wn = wave >> 1;
    int lrow = lane >> 3, lblk = lane & 7;
    int swz = ((lblk ^ lrow) * 8);
    int m0 = blockIdx.x * 128, n0 = blockIdx.y * 128;
    f32x4 acc[4][4] = {};

    for (int kt = 0; kt < 16; kt++) {
        int k0 = kt * 64;
        for (int i = 0; i < 4; i++) {
            int rbase = i * 32 + wave * 8;
            gload_lds16(&A[(size_t)(m0 + rbase + lrow) * 1024 + k0 + swz],
                        &As[rbase][0]);
            gload_lds16(&Bt[(size_t)(n0 + rbase + lrow) * 1024 + k0 + swz],
                        &Bs[rbase][0]);
        }
        __syncthreads();
        for (int ks = 0; ks < 2; ks++) {
            int pblk = ((ks * 4 + quad) ^ (l16 & 7)) * 8;
            bf16x8 af[4], bf_[4];
            for (int i = 0; i < 4; i++)
                af[i] = *(const bf16x8*)&As[64 * wm + 16 * i + l16][pblk];
            for (int j = 0; j < 4; j++)
                bf_[j] = *(const bf16x8*)&Bs[64 * wn + 16 * j + l16][pblk];
            for (int i = 0; i < 4; i++)
                for (int j = 0; j < 4; j++)
                    acc[i][j] = __builtin_amdgcn_mfma_f32_16x16x32_bf16(
                        af[i], bf_[j], acc[i][j], 0, 0, 0);
        }
        __syncthreads();
    }

    for (int i = 0; i < 4; i++)
        for (int j = 0; j < 4; j++) {
            int colb = n0 + 64 * wn + 16 * j + l16;
            for (int r = 0; r < 4; r++) {
                int row = m0 + 64 * wm + 16 * i + quad * 4 + r;
                outf[(size_t)row * 1024 + colb] = acc[i][j][r] + bias[colb];
            }
        }
}

// ----------------------------------------------------- flash attention
// 128 q/WG, 2 bands/wave. split=1: keys halved across blockIdx.z parity,
// unnormalized O (f32) + l partials to workspace. split=0: full keys, Y direct.
// Bias pre-permuted (*LOG2E) seeds the S accumulator; exp2f; P truncated.
__launch_bounds__(256, 4)
__global__ void attn_kernel(const unsigned short* __restrict__ Q,
                            const unsigned short* __restrict__ K,
                            const unsigned short* __restrict__ Vt,
                            const unsigned short* __restrict__ biasP,
                            unsigned short* __restrict__ Y,
                            float* __restrict__ Opart,
                            float* __restrict__ Lpart, int split) {
    __shared__ __align__(16) unsigned short Ks[64][64];
    __shared__ __align__(16) unsigned short Vs[64][64];
    __shared__ __align__(16) unsigned short Ps[4][32][72];
    int tid = threadIdx.x;
    int wave = tid >> 6, lane = tid & 63, quad = lane >> 4, l16 = lane & 15;
    int qt = blockIdx.x, h = blockIdx.y;
    int b, mt0, mtN;
    if (split) { b = blockIdx.z >> 1; int half = blockIdx.z & 1;
                 mt0 = half * 16; mtN = mt0 + 16; }
    else       { b = blockIdx.z; mt0 = 0; mtN = 32; }
    int q0 = qt * 128;
    size_t headoff = (size_t)(b * 16 + h) * 2048 * 64;
    const unsigned short* Kp = K + headoff;
    const unsigned short* Vp = Vt + headoff;
    int lrow = lane >> 3, lblk = lane & 7;
    int swz = (lblk ^ lrow) * 8;

    bf16x8 aq[2][2];
    for (int e = 0; e < 2; e++) {
        const unsigned short* qp =
            Q + headoff + (size_t)(q0 + e * 64 + wave * 16 + l16) * 64;
        aq[e][0] = *(const bf16x8*)&qp[quad * 8];
        aq[e][1] = *(const bf16x8*)&qp[32 + quad * 8];
    }
    bf16x8 ones;
    for (int j = 0; j < 8; j++) ones[j] = (short)0x3F80;   // bf16 1.0

    f32x4 oacc[2][4] = {};
    f32x4 lacc[2] = {};
    const unsigned short* bP = biasP + (size_t)(b * 16 + qt) * 32 * 8192;

    for (int mt = mt0; mt < mtN; mt++) {
        int m0 = mt * 64;
        for (int i = 0; i < 2; i++) {
            int rbase = wave * 16 + i * 8;
            gload_lds16(&Kp[(size_t)(m0 + rbase + lrow) * 64 + swz], &Ks[rbase][0]);
            gload_lds16(&Vp[(size_t)(rbase + lrow) * 2048 + m0 + swz], &Vs[rbase][0]);
        }
        const unsigned short* bt = bP + (size_t)mt * 8192;
        bf16x8 bz[2][2];
        for (int e = 0; e < 2; e++) {
            const unsigned short* p = bt + (size_t)((e * 4 + wave) * 64 + lane) * 16;
            bz[e][0] = *(const bf16x8*)&p[0];
            bz[e][1] = *(const bf16x8*)&p[8];
        }
        __syncthreads();

        // S = bias + Q K^T (bias seeds the accumulator)
        f32x4 sc[2][4];
        for (int e = 0; e < 2; e++)
            for (int c = 0; c < 4; c++) {
                f32x4 s;
                for (int r = 0; r < 4; r++)
                    s[r] = bf2f(((unsigned short*)&bz[e][c >> 1])[(c & 1) * 4 + r]);
                sc[e][c] = s;
            }
        for (int c = 0; c < 4; c++) {
            for (int ks = 0; ks < 2; ks++) {
                bf16x8 kf = *(const bf16x8*)&Ks[c * 16 + l16]
                                               [((ks * 4 + quad) ^ (l16 & 7)) * 8];
                sc[0][c] = __builtin_amdgcn_mfma_f32_16x16x32_bf16(aq[0][ks], kf, sc[0][c], 0, 0, 0);
                sc[1][c] = __builtin_amdgcn_mfma_f32_16x16x32_bf16(aq[1][ks], kf, sc[1][c], 0, 0, 0);
            }
        }

        // P = exp2(S) -> Ps (truncated bf16, swizzled scalar writes)
        for (int e = 0; e < 2; e++)
            for (int c = 0; c < 4; c++) {
                int colw = (((c * 2 + (l16 >> 3)) + quad) & 7) * 8 + (l16 & 7);
                for (int r = 0; r < 4; r++) {
                    float p = exp2f(sc[e][c][r]);
                    unsigned int u = __builtin_bit_cast(unsigned int, p);
                    Ps[wave][e * 16 + quad * 4 + r][colw] = (unsigned short)(u >> 16);
                }
            }

        // O += P V ; l += P 1
        for (int ks = 0; ks < 2; ks++) {
            int blkr = (ks * 4 + quad + (l16 >> 2)) & 7;
            bf16x8 pf0 = *(const bf16x8*)&Ps[wave][l16][blkr * 8];
            bf16x8 pf1 = *(const bf16x8*)&Ps[wave][16 + l16][blkr * 8];
            lacc[0] = __builtin_amdgcn_mfma_f32_16x16x32_bf16(pf0, ones, lacc[0], 0, 0, 0);
            lacc[1] = __builtin_amdgcn_mfma_f32_16x16x32_bf16(pf1, ones, lacc[1], 0, 0, 0);
            for (int cv = 0; cv < 4; cv++) {
                bf16x8 vf = *(const bf16x8*)&Vs[cv * 16 + l16]
                                               [((ks * 4 + quad) ^ (l16 & 7)) * 8];
                oacc[0][cv] = __builtin_amdgcn_mfma_f32_16x16x32_bf16(pf0, vf, oacc[0][cv], 0, 0, 0);
                oacc[1][cv] = __builtin_amdgcn_mfma_f32_16x16x32_bf16(pf1, vf, oacc[1][cv], 0, 0, 0);
            }
        }
        __syncthreads();
    }

    if (split) {
        size_t p = ((size_t)((b * 16 + h) * 16 + qt)) * 2 + (blockIdx.z & 1);
        float* Op = Opart + p * 8192;
        for (int e = 0; e < 2; e++)
            for (int cv = 0; cv < 4; cv++)
                for (int r = 0; r < 4; r++)
                    Op[(e * 64 + wave * 16 + quad * 4 + r) * 64 + cv * 16 + l16] =
                        oacc[e][cv][r];
        if (l16 == 0)
            for (int e = 0; e < 2; e++)
                for (int r = 0; r < 4; r++)
                    Lpart[p * 128 + e * 64 + wave * 16 + quad * 4 + r] = lacc[e][r];
    } else {
        for (int e = 0; e < 2; e++) {
            float invl[4];
            for (int r = 0; r < 4; r++) invl[r] = 1.0f / lacc[e][r];
            for (int cv = 0; cv < 4; cv++)
                for (int r = 0; r < 4; r++) {
                    int qrow = q0 + e * 64 + 16 * wave + quad * 4 + r;
                    int d = h * 64 + cv * 16 + l16;
                    Y[((size_t)b * 2048 + qrow) * 1024 + d] =
                        f2bf(oacc[e][cv][r] * invl[r]);
                }
        }
    }
}

// -------------------------------------------- combine split-K partials -> Y
__global__ void attn_combine(const float* __restrict__ Opart,
                             const float* __restrict__ Lpart,
                             unsigned short* __restrict__ Y) {
    int blk = blockIdx.x;                    // (b*16+h)*16+qt, 512 blocks
    int qt = blk & 15, h = (blk >> 4) & 15, b = blk >> 8;
    const float* O0 = Opart + (size_t)blk * 2 * 8192;
    const float* O1 = O0 + 8192;
    const float* L0 = Lpart + (size_t)blk * 2 * 128;
    const float* L1 = L0 + 128;
    int t = threadIdx.x;
    for (int i = 0; i < 8; i++) {
        int idx4 = i * 256 + t;              // float4 index (2048 total)
        int q = idx4 >> 4;
        int dk = (idx4 & 15) * 4;
        float4 a = *(const float4*)&O0[idx4 * 4];
        float4 c = *(const float4*)&O1[idx4 * 4];
        float inv = 1.0f / (L0[q] + L1[q]);
        uint2 u;
        u.x = (unsigned)f2bf((a.x + c.x) * inv) |
              ((unsigned)f2bf((a.y + c.y) * inv) << 16);
        u.y = (unsigned)f2bf((a.z + c.z) * inv) |
              ((unsigned)f2bf((a.w + c.w) * inv) << 16);
        int qrow = qt * 128 + q;
        *(uint2*)&Y[((size_t)b * 2048 + qrow) * 1024 + h * 64 + dk] = u;
    }
}

// ---------------------------------------------------------------- launcher
extern "C" void kernel_launch(void* const* d_in, const int* in_sizes, int n_in,
                              void* d_out, int out_size, void* d_ws, size_t ws_size,
                              hipStream_t stream) {
    const float* x     = (const float*)d_in[0];
    const float* alpha = (const float*)d_in[1];
    const float* bias  = (const float*)d_in[2];
    const float* Wq    = (const float*)d_in[3];
    const float* bq    = (const float*)d_in[4];
    const float* Wk    = (const float*)d_in[5];
    const float* bk    = (const float*)d_in[6];
    const float* Wv    = (const float*)d_in[7];
    const float* bv    = (const float*)d_in[8];
    const float* Wo    = (const float*)d_in[9];
    const float* bo    = (const float*)d_in[10];
    float* out = (float*)d_out;

    char* ws = (char*)d_ws;
    const size_t MB = 1048576;
    unsigned short* xb    = (unsigned short*)(ws);            // [0,8M), Yb later
    unsigned short* wqt   = (unsigned short*)(ws + 8 * MB);
    unsigned short* wkt   = (unsigned short*)(ws + 10 * MB);
    unsigned short* wvt   = (unsigned short*)(ws + 12 * MB);
    unsigned short* wot   = (unsigned short*)(ws + 14 * MB);
    unsigned short* Qb    = (unsigned short*)(ws + 16 * MB);
    unsigned short* Kb    = (unsigned short*)(ws + 24 * MB);
    unsigned short* Vtb   = (unsigned short*)(ws + 32 * MB);
    unsigned short* biasP = (unsigned short*)(ws + 40 * MB);  // 16 MB
    float*          Opart = (float*)(ws + 56 * MB);           // 32 MB
    float*          Lpart = (float*)(ws + 88 * MB);           // 0.5 MB
    unsigned short* Yb    = xb;
    int split = (ws_size >= 90 * MB) ? 1 : 0;

    convert_bf16<<<2048, 256, 0, stream>>>(x, xb, 524288);
    bias_permute<<<dim3(32, 16, 2), 256, 0, stream>>>(bias, biasP);
    transpose_convert4<<<dim3(32, 32, 4), dim3(32, 8), 0, stream>>>(
        Wq, Wk, Wv, Wo, wqt, wkt, wvt, wot);

    gemm_qkv<<<dim3(32, 24), 256, 0, stream>>>(
        xb, wqt, wkt, wvt, bq, bk, bv, alpha, Qb, Kb, Vtb);

    if (split) {
        attn_kernel<<<dim3(16, 16, 4), 256, 0, stream>>>(
            Qb, Kb, Vtb, biasP, Yb, Opart, Lpart, 1);
        attn_combine<<<512, 256, 0, stream>>>(Opart, Lpart, Yb);
    } else {
        attn_kernel<<<dim3(16, 16, 2), 256, 0, stream>>>(
            Qb, Kb, Vtb, biasP, Yb, Opart, Lpart, 0);
    }

    gemm_out<<<dim3(32, 8), 256, 0, stream>>>(Yb, wot, bo, out);
}

// Round 8
// 247.914 us; speedup vs baseline: 1.7337x; 1.0289x over previous
//
#include <hip/hip_runtime.h>

typedef __attribute__((ext_vector_type(8))) short bf16x8;
typedef __attribute__((ext_vector_type(4))) float f32x4;

#define LOG2E 1.4426950408889634f

static __device__ __forceinline__ unsigned short f2bf(float f) {
    unsigned int u = __builtin_bit_cast(unsigned int, f);
    u += 0x7fffu + ((u >> 16) & 1u);   // round-to-nearest-even
    return (unsigned short)(u >> 16);
}
static __device__ __forceinline__ float bf2f(unsigned short h) {
    unsigned int u = ((unsigned int)h) << 16;
    return __builtin_bit_cast(float, u);
}
// async global->LDS, 16B per lane; LDS dest = wave-uniform base + lane*16
static __device__ __forceinline__ void gload_lds16(const void* g, void* l) {
    __builtin_amdgcn_global_load_lds(
        (const __attribute__((address_space(1))) void*)g,
        (__attribute__((address_space(3))) void*)l, 16, 0, 0);
}

// ------------------------------------------- fp32 -> bf16 (x)
__global__ void convert_bf16(const float* __restrict__ src,
                             unsigned short* __restrict__ dst, int n8) {
    int i = blockIdx.x * blockDim.x + threadIdx.x;
    if (i >= n8) return;
    const float4* s4 = (const float4*)src;
    float4 a = s4[2 * i], b = s4[2 * i + 1];
    uint4 u;
    u.x = (unsigned)f2bf(a.x) | ((unsigned)f2bf(a.y) << 16);
    u.y = (unsigned)f2bf(a.z) | ((unsigned)f2bf(a.w) << 16);
    u.z = (unsigned)f2bf(b.x) | ((unsigned)f2bf(b.y) << 16);
    u.w = (unsigned)f2bf(b.z) | ((unsigned)f2bf(b.w) << 16);
    *(uint4*)(dst + 8 * (size_t)i) = u;
}

// -------------------- bias: fp32 [b][q][k] -> bf16*LOG2E in C-fragment order
__global__ void bias_permute(const float* __restrict__ src,
                             unsigned short* __restrict__ dst) {
    int mt = blockIdx.x, qt = blockIdx.y, b = blockIdx.z;
    int tid = threadIdx.x, w = tid >> 6, lane = tid & 63;
    int quad = lane >> 4, l16 = lane & 15;
    const float* s = src + (size_t)b * 2048 * 2048;
    unsigned short* d = dst + (((size_t)(b * 16 + qt) * 32 + mt) * 8192);
    for (int e = 0; e < 2; e++) {
        unsigned short vals[16];
        for (int c = 0; c < 4; c++)
            for (int r = 0; r < 4; r++) {
                int q = qt * 128 + e * 64 + w * 16 + quad * 4 + r;
                int k = mt * 64 + c * 16 + l16;
                vals[c * 4 + r] = f2bf(s[(size_t)q * 2048 + k] * LOG2E);
            }
        unsigned short* o = d + ((size_t)((e * 4 + w) * 64 + lane)) * 16;
        *(bf16x8*)&o[0] = *(bf16x8*)&vals[0];
        *(bf16x8*)&o[8] = *(bf16x8*)&vals[8];
    }
}

// ---------------------------- transpose+convert all 4 weights (1024x1024)
__global__ void transpose_convert4(const float* __restrict__ W0,
                                   const float* __restrict__ W1,
                                   const float* __restrict__ W2,
                                   const float* __restrict__ W3,
                                   unsigned short* __restrict__ T0,
                                   unsigned short* __restrict__ T1,
                                   unsigned short* __restrict__ T2,
                                   unsigned short* __restrict__ T3) {
    const float* W = (blockIdx.z == 0) ? W0 : (blockIdx.z == 1) ? W1
                     : (blockIdx.z == 2) ? W2 : W3;
    unsigned short* Wt = (blockIdx.z == 0) ? T0 : (blockIdx.z == 1) ? T1
                         : (blockIdx.z == 2) ? T2 : T3;
    __shared__ float t[32][33];
    int tx = threadIdx.x, ty = threadIdx.y;          // 32 x 8
    int x0 = blockIdx.x * 32, y0 = blockIdx.y * 32;
    for (int i = 0; i < 4; i++)
        t[ty + 8 * i][tx] = W[(size_t)(y0 + ty + 8 * i) * 1024 + x0 + tx];
    __syncthreads();
    for (int i = 0; i < 4; i++)
        Wt[(size_t)(x0 + ty + 8 * i) * 1024 + y0 + tx] = f2bf(t[tx][ty + 8 * i]);
}

// ------------------------------------------------------------ QKV GEMM
// Q scaled 0.125*LOG2E -> [b][h][n][dk]; K scaled (1+alpha) -> [b][h][n][dk];
// V scaled (1+alpha) -> TRANSPOSED [b][h][dk][n].
// For Q/K the MFMA operands are SWAPPED (C^T layout): lane then holds 4
// consecutive dk at one token -> uint2 stores, one alpha load per fragment.
__launch_bounds__(256)
__global__ void gemm_qkv(const unsigned short* __restrict__ A,
                         const unsigned short* __restrict__ WqT,
                         const unsigned short* __restrict__ WkT,
                         const unsigned short* __restrict__ WvT,
                         const float* __restrict__ bq,
                         const float* __restrict__ bk,
                         const float* __restrict__ bv,
                         const float* __restrict__ alpha,
                         unsigned short* __restrict__ Qb,
                         unsigned short* __restrict__ Kb,
                         unsigned short* __restrict__ Vtb) {
    int which = blockIdx.y >> 3;
    const unsigned short* Bt = (which == 0) ? WqT : (which == 1) ? WkT : WvT;
    const float* bias = (which == 0) ? bq : (which == 1) ? bk : bv;

    __shared__ __align__(16) unsigned short As[128][64];
    __shared__ __align__(16) unsigned short Bs[128][64];
    int tid = threadIdx.x;
    int wave = tid >> 6, lane = tid & 63, quad = lane >> 4, l16 = lane & 15;
    int wm = wave & 1, wn = wave >> 1;
    int lrow = lane >> 3, lblk = lane & 7;
    int swz = ((lblk ^ lrow) * 8);
    int m0 = blockIdx.x * 128, n0 = (blockIdx.y & 7) * 128;
    f32x4 acc[4][4] = {};

    for (int kt = 0; kt < 16; kt++) {
        int k0 = kt * 64;
        for (int i = 0; i < 4; i++) {
            int rbase = i * 32 + wave * 8;
            gload_lds16(&A[(size_t)(m0 + rbase + lrow) * 1024 + k0 + swz],
                        &As[rbase][0]);
            gload_lds16(&Bt[(size_t)(n0 + rbase + lrow) * 1024 + k0 + swz],
                        &Bs[rbase][0]);
        }
        __syncthreads();
        for (int ks = 0; ks < 2; ks++) {
            int pblk = ((ks * 4 + quad) ^ (l16 & 7)) * 8;
            bf16x8 af[4], bf_[4];
            for (int i = 0; i < 4; i++)
                af[i] = *(const bf16x8*)&As[64 * wm + 16 * i + l16][pblk];
            for (int j = 0; j < 4; j++)
                bf_[j] = *(const bf16x8*)&Bs[64 * wn + 16 * j + l16][pblk];
            if (which == 2) {
                for (int i = 0; i < 4; i++)
                    for (int j = 0; j < 4; j++)
                        acc[i][j] = __builtin_amdgcn_mfma_f32_16x16x32_bf16(
                            af[i], bf_[j], acc[i][j], 0, 0, 0);
            } else {   // swapped: acc[i][j] = C^T block (row=weight col, col=token)
                for (int i = 0; i < 4; i++)
                    for (int j = 0; j < 4; j++)
                        acc[i][j] = __builtin_amdgcn_mfma_f32_16x16x32_bf16(
                            bf_[j], af[i], acc[i][j], 0, 0, 0);
            }
        }
        __syncthreads();
    }

    if (which == 2) {
        for (int i = 0; i < 4; i++)
            for (int j = 0; j < 4; j++) {
                int colb = n0 + 64 * wn + 16 * j + l16;
                int h = colb >> 6, dk = colb & 63;
                int row0 = m0 + 64 * wm + 16 * i + quad * 4;
                int bb = row0 >> 11, nn0 = row0 & 2047;
                unsigned short v4[4];
                for (int r = 0; r < 4; r++) {
                    float v = acc[i][j][r] + bias[colb];
                    v4[r] = f2bf(v * (1.0f + alpha[bb * 2048 + nn0 + r]));
                }
                uint2 u;
                u.x = (unsigned)v4[0] | ((unsigned)v4[1] << 16);
                u.y = (unsigned)v4[2] | ((unsigned)v4[3] << 16);
                *(uint2*)&Vtb[((size_t)(bb * 16 + h) * 64 + dk) * 2048 + nn0] = u;
            }
    } else {
        unsigned short* outb = (which == 0) ? Qb : Kb;
        for (int i = 0; i < 4; i++)
            for (int j = 0; j < 4; j++) {
                int row = m0 + 64 * wm + 16 * i + l16;          // token
                int bb = row >> 11, nn = row & 2047;
                int colb0 = n0 + 64 * wn + 16 * j + quad * 4;   // 4 consec cols
                int h = colb0 >> 6, dk0 = colb0 & 63;
                float4 b4 = *(const float4*)&bias[colb0];
                float s = (which == 0) ? (0.125f * LOG2E)
                                       : (1.0f + alpha[bb * 2048 + nn]);
                unsigned short v4[4];
                v4[0] = f2bf((acc[i][j][0] + b4.x) * s);
                v4[1] = f2bf((acc[i][j][1] + b4.y) * s);
                v4[2] = f2bf((acc[i][j][2] + b4.z) * s);
                v4[3] = f2bf((acc[i][j][3] + b4.w) * s);
                uint2 u;
                u.x = (unsigned)v4[0] | ((unsigned)v4[1] << 16);
                u.y = (unsigned)v4[2] | ((unsigned)v4[3] << 16);
                *(uint2*)&outb[((size_t)(bb * 16 + h) * 2048 + nn) * 64 + dk0] = u;
            }
    }
}

// ------------------------------------------------ out projection GEMM (fp32)
// Swapped operands: lane holds 4 consecutive out-cols at one token -> float4.
__launch_bounds__(256)
__global__ void gemm_out(const unsigned short* __restrict__ A,
                         const unsigned short* __restrict__ Bt,
                         const float* __restrict__ bias,
                         float* __restrict__ outf) {
    __shared__ __align__(16) unsigned short As[128][64];
    __shared__ __align__(16) unsigned short Bs[128][64];
    int tid = threadIdx.x;
    int wave = tid >> 6, lane = tid & 63, quad = lane >> 4, l16 = lane & 15;
    int wm = wave & 1, wn = wave >> 1;
    int lrow = lane >> 3, lblk = lane & 7;
    int swz = ((lblk ^ lrow) * 8);
    int m0 = blockIdx.x * 128, n0 = blockIdx.y * 128;
    f32x4 acc[4][4] = {};

    for (int kt = 0; kt < 16; kt++) {
        int k0 = kt * 64;
        for (int i = 0; i < 4; i++) {
            int rbase = i * 32 + wave * 8;
            gload_lds16(&A[(size_t)(m0 + rbase + lrow) * 1024 + k0 + swz],
                        &As[rbase][0]);
            gload_lds16(&Bt[(size_t)(n0 + rbase + lrow) * 1024 + k0 + swz],
                        &Bs[rbase][0]);
        }
        __syncthreads();
        for (int ks = 0; ks < 2; ks++) {
            int pblk = ((ks * 4 + quad) ^ (l16 & 7)) * 8;
            bf16x8 af[4], bf_[4];
            for (int i = 0; i < 4; i++)
                af[i] = *(const bf16x8*)&As[64 * wm + 16 * i + l16][pblk];
            for (int j = 0; j < 4; j++)
                bf_[j] = *(const bf16x8*)&Bs[64 * wn + 16 * j + l16][pblk];
            for (int i = 0; i < 4; i++)
                for (int j = 0; j < 4; j++)
                    acc[i][j] = __builtin_amdgcn_mfma_f32_16x16x32_bf16(
                        bf_[j], af[i], acc[i][j], 0, 0, 0);
        }
        __syncthreads();
    }

    for (int i = 0; i < 4; i++)
        for (int j = 0; j < 4; j++) {
            int row = m0 + 64 * wm + 16 * i + l16;          // token
            int colb0 = n0 + 64 * wn + 16 * j + quad * 4;   // 4 consec cols
            float4 b4 = *(const float4*)&bias[colb0];
            float4 o;
            o.x = acc[i][j][0] + b4.x;
            o.y = acc[i][j][1] + b4.y;
            o.z = acc[i][j][2] + b4.z;
            o.w = acc[i][j][3] + b4.w;
            *(float4*)&outf[(size_t)row * 1024 + colb0] = o;
        }
}

// ----------------------------------------------------- flash attention
__launch_bounds__(256, 4)
__global__ void attn_kernel(const unsigned short* __restrict__ Q,
                            const unsigned short* __restrict__ K,
                            const unsigned short* __restrict__ Vt,
                            const unsigned short* __restrict__ biasP,
                            unsigned short* __restrict__ Y,
                            float* __restrict__ Opart,
                            float* __restrict__ Lpart, int split) {
    __shared__ __align__(16) unsigned short Ks[64][64];
    __shared__ __align__(16) unsigned short Vs[64][64];
    __shared__ __align__(16) unsigned short Ps[4][32][72];
    int tid = threadIdx.x;
    int wave = tid >> 6, lane = tid & 63, quad = lane >> 4, l16 = lane & 15;
    int qt = blockIdx.x, h = blockIdx.y;
    int b, mt0, mtN;
    if (split) { b = blockIdx.z >> 1; int half = blockIdx.z & 1;
                 mt0 = half * 16; mtN = mt0 + 16; }
    else       { b = blockIdx.z; mt0 = 0; mtN = 32; }
    int q0 = qt * 128;
    size_t headoff = (size_t)(b * 16 + h) * 2048 * 64;
    const unsigned short* Kp = K + headoff;
    const unsigned short* Vp = Vt + headoff;
    int lrow = lane >> 3, lblk = lane & 7;
    int swz = (lblk ^ lrow) * 8;

    bf16x8 aq[2][2];
    for (int e = 0; e < 2; e++) {
        const unsigned short* qp =
            Q + headoff + (size_t)(q0 + e * 64 + wave * 16 + l16) * 64;
        aq[e][0] = *(const bf16x8*)&qp[quad * 8];
        aq[e][1] = *(const bf16x8*)&qp[32 + quad * 8];
    }
    bf16x8 ones;
    for (int j = 0; j < 8; j++) ones[j] = (short)0x3F80;   // bf16 1.0

    f32x4 oacc[2][4] = {};
    f32x4 lacc[2] = {};
    const unsigned short* bP = biasP + (size_t)(b * 16 + qt) * 32 * 8192;

    for (int mt = mt0; mt < mtN; mt++) {
        int m0 = mt * 64;
        for (int i = 0; i < 2; i++) {
            int rbase = wave * 16 + i * 8;
            gload_lds16(&Kp[(size_t)(m0 + rbase + lrow) * 64 + swz], &Ks[rbase][0]);
            gload_lds16(&Vp[(size_t)(rbase + lrow) * 2048 + m0 + swz], &Vs[rbase][0]);
        }
        const unsigned short* bt = bP + (size_t)mt * 8192;
        bf16x8 bz[2][2];
        for (int e = 0; e < 2; e++) {
            const unsigned short* p = bt + (size_t)((e * 4 + wave) * 64 + lane) * 16;
            bz[e][0] = *(const bf16x8*)&p[0];
            bz[e][1] = *(const bf16x8*)&p[8];
        }
        __syncthreads();

        // S = bias + Q K^T (bias seeds the accumulator)
        f32x4 sc[2][4];
        for (int e = 0; e < 2; e++)
            for (int c = 0; c < 4; c++) {
                f32x4 s;
                for (int r = 0; r < 4; r++)
                    s[r] = bf2f(((unsigned short*)&bz[e][c >> 1])[(c & 1) * 4 + r]);
                sc[e][c] = s;
            }
        for (int c = 0; c < 4; c++) {
            for (int ks = 0; ks < 2; ks++) {
                bf16x8 kf = *(const bf16x8*)&Ks[c * 16 + l16]
                                               [((ks * 4 + quad) ^ (l16 & 7)) * 8];
                sc[0][c] = __builtin_amdgcn_mfma_f32_16x16x32_bf16(aq[0][ks], kf, sc[0][c], 0, 0, 0);
                sc[1][c] = __builtin_amdgcn_mfma_f32_16x16x32_bf16(aq[1][ks], kf, sc[1][c], 0, 0, 0);
            }
        }

        // P = exp2(S) -> Ps (truncated bf16, swizzled scalar writes)
        for (int e = 0; e < 2; e++)
            for (int c = 0; c < 4; c++) {
                int colw = (((c * 2 + (l16 >> 3)) + quad) & 7) * 8 + (l16 & 7);
                for (int r = 0; r < 4; r++) {
                    float p = exp2f(sc[e][c][r]);
                    unsigned int u = __builtin_bit_cast(unsigned int, p);
                    Ps[wave][e * 16 + quad * 4 + r][colw] = (unsigned short)(u >> 16);
                }
            }

        // O += P V ; l += P 1
        for (int ks = 0; ks < 2; ks++) {
            int blkr = (ks * 4 + quad + (l16 >> 2)) & 7;
            bf16x8 pf0 = *(const bf16x8*)&Ps[wave][l16][blkr * 8];
            bf16x8 pf1 = *(const bf16x8*)&Ps[wave][16 + l16][blkr * 8];
            lacc[0] = __builtin_amdgcn_mfma_f32_16x16x32_bf16(pf0, ones, lacc[0], 0, 0, 0);
            lacc[1] = __builtin_amdgcn_mfma_f32_16x16x32_bf16(pf1, ones, lacc[1], 0, 0, 0);
            for (int cv = 0; cv < 4; cv++) {
                bf16x8 vf = *(const bf16x8*)&Vs[cv * 16 + l16]
                                               [((ks * 4 + quad) ^ (l16 & 7)) * 8];
                oacc[0][cv] = __builtin_amdgcn_mfma_f32_16x16x32_bf16(pf0, vf, oacc[0][cv], 0, 0, 0);
                oacc[1][cv] = __builtin_amdgcn_mfma_f32_16x16x32_bf16(pf1, vf, oacc[1][cv], 0, 0, 0);
            }
        }
        __syncthreads();
    }

    if (split) {
        size_t p = ((size_t)((b * 16 + h) * 16 + qt)) * 2 + (blockIdx.z & 1);
        float* Op = Opart + p * 8192;
        for (int e = 0; e < 2; e++)
            for (int cv = 0; cv < 4; cv++)
                for (int r = 0; r < 4; r++)
                    Op[(e * 64 + wave * 16 + quad * 4 + r) * 64 + cv * 16 + l16] =
                        oacc[e][cv][r];
        if (l16 == 0)
            for (int e = 0; e < 2; e++)
                for (int r = 0; r < 4; r++)
                    Lpart[p * 128 + e * 64 + wave * 16 + quad * 4 + r] = lacc[e][r];
    } else {
        for (int e = 0; e < 2; e++) {
            float invl[4];
            for (int r = 0; r < 4; r++) invl[r] = 1.0f / lacc[e][r];
            for (int cv = 0; cv < 4; cv++)
                for (int r = 0; r < 4; r++) {
                    int qrow = q0 + e * 64 + 16 * wave + quad * 4 + r;
                    int d = h * 64 + cv * 16 + l16;
                    Y[((size_t)b * 2048 + qrow) * 1024 + d] =
                        f2bf(oacc[e][cv][r] * invl[r]);
                }
        }
    }
}

// -------------------------------------------- combine split-K partials -> Y
__global__ void attn_combine(const float* __restrict__ Opart,
                             const float* __restrict__ Lpart,
                             unsigned short* __restrict__ Y) {
    int blk = blockIdx.x;                    // (b*16+h)*16+qt, 512 blocks
    int qt = blk & 15, h = (blk >> 4) & 15, b = blk >> 8;
    const float* O0 = Opart + (size_t)blk * 2 * 8192;
    const float* O1 = O0 + 8192;
    const float* L0 = Lpart + (size_t)blk * 2 * 128;
    const float* L1 = L0 + 128;
    int t = threadIdx.x;
    for (int i = 0; i < 8; i++) {
        int idx4 = i * 256 + t;              // float4 index (2048 total)
        int q = idx4 >> 4;
        int dk = (idx4 & 15) * 4;
        float4 a = *(const float4*)&O0[idx4 * 4];
        float4 c = *(const float4*)&O1[idx4 * 4];
        float inv = 1.0f / (L0[q] + L1[q]);
        uint2 u;
        u.x = (unsigned)f2bf((a.x + c.x) * inv) |
              ((unsigned)f2bf((a.y + c.y) * inv) << 16);
        u.y = (unsigned)f2bf((a.z + c.z) * inv) |
              ((unsigned)f2bf((a.w + c.w) * inv) << 16);
        int qrow = qt * 128 + q;
        *(uint2*)&Y[((size_t)b * 2048 + qrow) * 1024 + h * 64 + dk] = u;
    }
}

// ---------------------------------------------------------------- launcher
extern "C" void kernel_launch(void* const* d_in, const int* in_sizes, int n_in,
                              void* d_out, int out_size, void* d_ws, size_t ws_size,
                              hipStream_t stream) {
    const float* x     = (const float*)d_in[0];
    const float* alpha = (const float*)d_in[1];
    const float* bias  = (const float*)d_in[2];
    const float* Wq    = (const float*)d_in[3];
    const float* bq    = (const float*)d_in[4];
    const float* Wk    = (const float*)d_in[5];
    const float* bk    = (const float*)d_in[6];
    const float* Wv    = (const float*)d_in[7];
    const float* bv    = (const float*)d_in[8];
    const float* Wo    = (const float*)d_in[9];
    const float* bo    = (const float*)d_in[10];
    float* out = (float*)d_out;

    char* ws = (char*)d_ws;
    const size_t MB = 1048576;
    unsigned short* xb    = (unsigned short*)(ws);            // [0,8M), Yb later
    unsigned short* wqt   = (unsigned short*)(ws + 8 * MB);
    unsigned short* wkt   = (unsigned short*)(ws + 10 * MB);
    unsigned short* wvt   = (unsigned short*)(ws + 12 * MB);
    unsigned short* wot   = (unsigned short*)(ws + 14 * MB);
    unsigned short* Qb    = (unsigned short*)(ws + 16 * MB);
    unsigned short* Kb    = (unsigned short*)(ws + 24 * MB);
    unsigned short* Vtb   = (unsigned short*)(ws + 32 * MB);
    unsigned short* biasP = (unsigned short*)(ws + 40 * MB);  // 16 MB
    float*          Opart = (float*)(ws + 56 * MB);           // 32 MB
    float*          Lpart = (float*)(ws + 88 * MB);           // 0.5 MB
    unsigned short* Yb    = xb;
    int split = (ws_size >= 90 * MB) ? 1 : 0;

    convert_bf16<<<2048, 256, 0, stream>>>(x, xb, 524288);
    bias_permute<<<dim3(32, 16, 2), 256, 0, stream>>>(bias, biasP);
    transpose_convert4<<<dim3(32, 32, 4), dim3(32, 8), 0, stream>>>(
        Wq, Wk, Wv, Wo, wqt, wkt, wvt, wot);

    gemm_qkv<<<dim3(32, 24), 256, 0, stream>>>(
        xb, wqt, wkt, wvt, bq, bk, bv, alpha, Qb, Kb, Vtb);

    if (split) {
        attn_kernel<<<dim3(16, 16, 4), 256, 0, stream>>>(
            Qb, Kb, Vtb, biasP, Yb, Opart, Lpart, 1);
        attn_combine<<<512, 256, 0, stream>>>(Opart, Lpart, Yb);
    } else {
        attn_kernel<<<dim3(16, 16, 2), 256, 0, stream>>>(
            Qb, Kb, Vtb, biasP, Yb, Opart, Lpart, 0);
    }

    gemm_out<<<dim3(32, 8), 256, 0, stream>>>(Yb, wot, bo, out);
}